// Round 7
// baseline (294.008 us; speedup 1.0000x reference)
//
#include <hip/hip_runtime.h>

// Problem constants (B, L, D, H) = (16, 512, 128, 8)
#define B_  16
#define L_  512
#define D_  128
#define H_  8
#define HD_ 1024   // H*D
#define NH_ 128    // H*B
#define M_  8192   // B*L

typedef unsigned short u16;
typedef __attribute__((ext_vector_type(8))) short s16x8;   // 8 bf16 = 4 VGPRs
typedef __attribute__((ext_vector_type(4))) float f32x4;   // MFMA accumulator

// ---------- bf16 helpers ----------
__device__ __forceinline__ float bf2f(u16 u) {
    union { unsigned u; float f; } x; x.u = ((unsigned)u) << 16; return x.f;
}
__device__ __forceinline__ u16 f2bf(float f) {
    unsigned u = __float_as_uint(f);
    return (u16)((u + 0x7FFFu + ((u >> 16) & 1u)) >> 16);   // RNE
}
__device__ __forceinline__ float ld1(const void* p, size_t i, int dt) {
    if (dt) return bf2f(((const u16*)p)[i]);
    return ((const float*)p)[i];
}

// dtype-switched 8-element fragment load (dt==1: bf16, dt==0: fp32->bf16)
__device__ __forceinline__ s16x8 ld_frag(const void* p, size_t off, int dt) {
    if (dt) return *(const s16x8*)((const u16*)p + off);
    const float* f = (const float*)p + off;
    float4 a = *(const float4*)f;
    float4 b = *(const float4*)(f + 4);
    union { u16 u[8]; s16x8 v; } t;
    t.u[0] = f2bf(a.x); t.u[1] = f2bf(a.y); t.u[2] = f2bf(a.z); t.u[3] = f2bf(a.w);
    t.u[4] = f2bf(b.x); t.u[5] = f2bf(b.y); t.u[6] = f2bf(b.z); t.u[7] = f2bf(b.w);
    return t.v;
}

// ---------------------------------------------------------------
// MFMA bt-core: C(MI*16 x MJ*16) = A @ B^T for one wave, dtype-switched.
// A/B operand: row = lane&15, k = (lane>>4)*8 + j  (16B contiguous)
// C/D: col = lane&15, row = (lane>>4)*4 + reg   (m89/m91-verified)
// ---------------------------------------------------------------
template<int MI, int MJ>
__device__ __forceinline__ void mfma_core(
    const void* __restrict__ A, size_t offA, int lda, int dtA,
    const void* __restrict__ B, size_t offB, int ldb, int dtB,
    int K, int lane, f32x4 acc[MI][MJ]) {
    const int mr = lane & 15, quad = lane >> 4;
    for (int k0 = 0; k0 < K; k0 += 32) {
        s16x8 av[MI], bv[MJ];
#pragma unroll
        for (int i = 0; i < MI; i++)
            av[i] = ld_frag(A, offA + (size_t)(i * 16 + mr) * lda + k0 + quad * 8, dtA);
#pragma unroll
        for (int j = 0; j < MJ; j++)
            bv[j] = ld_frag(B, offB + (size_t)(j * 16 + mr) * ldb + k0 + quad * 8, dtB);
#pragma unroll
        for (int i = 0; i < MI; i++)
#pragma unroll
            for (int j = 0; j < MJ; j++)
                acc[i][j] = __builtin_amdgcn_mfma_f32_16x16x32_bf16(av[i], bv[j], acc[i][j], 0, 0, 0);
    }
}

// ---------------------------------------------------------------
// K0: detect float dtype (fp32 vs packed bf16) + mask dtype (i32 vs u8).
// ---------------------------------------------------------------
__global__ void k0_detect(const unsigned int* __restrict__ pad,
                          const unsigned int* __restrict__ xw,
                          int* __restrict__ flags) {
    __shared__ int sMask, sCnt;
    if (threadIdx.x == 0) { sMask = 0; sCnt = 0; }
    __syncthreads();
    int bad = 0;
#pragma unroll
    for (int i = 0; i < 4; i++) {
        unsigned u = pad[threadIdx.x * 4 + i];
        bad |= (u > 1u) ? 1 : 0;
    }
    int cnt = 0;
#pragma unroll
    for (int i = 0; i < 16; i++) {
        unsigned w = xw[threadIdx.x * 16 + i];
        unsigned e = (w >> 7) & 0xFFu;
        cnt += (e >= 100u && e <= 131u) ? 1 : 0;
    }
    if (bad) atomicOr(&sMask, 1);
    atomicAdd(&sCnt, cnt);
    __syncthreads();
    if (threadIdx.x == 0) {
        flags[0] = (sCnt > 2048) ? 1 : 0;   // 1 => floats are bf16
        flags[1] = sMask;                   // 1 => mask is uint8
    }
}

// ---------------------------------------------------------------
// Kprep_mask: pack pad_mask into bitmask [16][512][16 u32 words],
// vectorized loads; also zero lsum[128*512].
// ---------------------------------------------------------------
__global__ __launch_bounds__(256) void kprep_mask(const void* __restrict__ pad,
                                                  const int* __restrict__ flags,
                                                  unsigned* __restrict__ mb,
                                                  float* __restrict__ lsum) {
    int w = blockIdx.x * 256 + threadIdx.x;     // < 131072
    if (w < 65536) lsum[w] = 0.f;
    unsigned m = 0;
    if (flags[1]) {
        union { uint4 v[2]; unsigned a[8]; } u;
        u.v[0] = ((const uint4*)pad)[w * 2];
        u.v[1] = ((const uint4*)pad)[w * 2 + 1];
#pragma unroll
        for (int b = 0; b < 32; b++)
            m |= (((u.a[b >> 2] >> ((b & 3) * 8)) & 0xFFu) ? 1u : 0u) << b;
    } else {
        union { uint4 v[8]; unsigned a[32]; } u;
#pragma unroll
        for (int i = 0; i < 8; i++) u.v[i] = ((const uint4*)pad)[w * 8 + i];
#pragma unroll
        for (int b = 0; b < 32; b++) m |= (u.a[b] ? 1u : 0u) << b;
    }
    mb[w] = m;
}

// ---------------------------------------------------------------
// K1: QKV projection, 1-wave blocks, raw (dtype-switched) x/W/bias.
// Tile: 64 m x 64 e.  q,k head-major [n][l][d]; v TRANSPOSED [n][d][l].
// grid (128 m-tiles, 16 e-tiles, 3 z), 64 threads.
// ---------------------------------------------------------------
__global__ __launch_bounds__(64) void k1_proj(
    const void* __restrict__ x,
    const void* __restrict__ Wq, const void* __restrict__ Wk, const void* __restrict__ Wv,
    const void* __restrict__ bq, const void* __restrict__ bk, const void* __restrict__ bv,
    const int* __restrict__ flags,
    u16* __restrict__ qb, u16* __restrict__ kb, u16* __restrict__ vtb) {
    const int dt = flags[0];
    const int m0 = blockIdx.x * 64;
    const int ye = blockIdx.y;           // e-tile: h = ye>>1, d0 = (ye&1)*64
    const int z  = blockIdx.z;
    const void* W    = (z == 0) ? Wq : (z == 1) ? Wk : Wv;
    const void* bias = (z == 0) ? bq : (z == 1) ? bk : bv;

    const int lane = threadIdx.x;
    const int mr = lane & 15, quad = lane >> 4;

    f32x4 acc[4][4];
#pragma unroll
    for (int i = 0; i < 4; i++)
#pragma unroll
        for (int j = 0; j < 4; j++) acc[i][j] = (f32x4){0.f, 0.f, 0.f, 0.f};

    mfma_core<4,4>(x, (size_t)m0 * D_, D_, dt,
                   W, (size_t)ye * 64 * D_, D_, dt, D_, lane, acc);

    __shared__ __align__(16) u16 T[64][72];
#pragma unroll
    for (int i = 0; i < 4; i++)
#pragma unroll
        for (int j = 0; j < 4; j++) {
            int colL = j * 16 + mr;
            float bv_ = ld1(bias, ye * 64 + colL, dt);
#pragma unroll
            for (int r = 0; r < 4; r++) {
                int row = i * 16 + quad * 4 + r;
                float v = acc[i][j][r] + bv_;
                if (z < 2) T[row][colL] = f2bf(v);
                else       T[colL][row] = f2bf(v);   // transposed for vt
            }
        }
    __syncthreads();

    const int bb = m0 >> 9, l0 = m0 & 511;
    const int h = ye >> 1, d0 = (ye & 1) * 64;
    const int t = threadIdx.x;
    if (z < 2) {
        u16* out = z ? kb : qb;
        u16* dst = out + ((size_t)(h * B_ + bb) * L_ + l0 + t) * D_ + d0;
#pragma unroll
        for (int c = 0; c < 64; c += 8)
            *(uint4*)(dst + c) = *(const uint4*)&T[t][c];
    } else {
        u16* dst = vtb + ((size_t)(h * B_ + bb) * D_ + d0 + t) * L_ + l0;
#pragma unroll
        for (int c = 0; c < 64; c += 8)
            *(uint4*)(dst + c) = *(const uint4*)&T[t][c];
    }
}

// ---------------------------------------------------------------
// K2: E[n,q,k] = exp((mask? -1e9 : q.k) * rs), bf16 materialized, plus
// column-sum partials atomically added to lsum[n,k].  1-wave blocks,
// tile 32 q x 64 k.  grid (128 n, 8 ks, 16 qs), 64 threads.
// ---------------------------------------------------------------
__global__ __launch_bounds__(64) void k2_escore(
    const u16* __restrict__ qb, const u16* __restrict__ kb,
    const unsigned* __restrict__ mbits,
    u16* __restrict__ E, float* __restrict__ lsum) {
    const int n  = blockIdx.x;
    const int ks = blockIdx.y;       // k-strip of 64
    const int qs = blockIdx.z;       // q-strip of 32
    const int bb = n & (B_ - 1);
    const int lane = threadIdx.x;
    const int mr = lane & 15, quad = lane >> 4;
    const float rs = 0.08838834764831845f;   // 1/sqrt(128)

    __shared__ __align__(16) u16 Te[32][72];
    __shared__ unsigned mw[64];              // [32 q][2 words]
    mw[lane] = mbits[((size_t)(bb << 9) + qs * 32 + (lane >> 1)) * 16 + ks * 2 + (lane & 1)];
    __syncthreads();

    f32x4 acc[2][4];
#pragma unroll
    for (int i = 0; i < 2; i++)
#pragma unroll
        for (int j = 0; j < 4; j++) acc[i][j] = (f32x4){0.f, 0.f, 0.f, 0.f};

    mfma_core<2,4>(qb, ((size_t)n * L_ + qs * 32) * D_, D_, 1,
                   kb, ((size_t)n * L_ + ks * 64) * D_, D_, 1, D_, lane, acc);

    float colsum[4] = {0.f, 0.f, 0.f, 0.f};
#pragma unroll
    for (int j = 0; j < 4; j++) {
        const int kc = j * 16 + mr;              // 0..63
        const int lw = j >> 1;
        const int bit = (j & 1) * 16 + mr;
#pragma unroll
        for (int i = 0; i < 2; i++)
#pragma unroll
            for (int r = 0; r < 4; r++) {
                int ql = i * 16 + quad * 4 + r;  // 0..31
                float e = ((mw[ql * 2 + lw] >> bit) & 1u)
                          ? 0.f : __expf(acc[i][j][r] * rs);
                colsum[j] += e;
                Te[ql][kc] = f2bf(e);
            }
    }
#pragma unroll
    for (int j = 0; j < 4; j++) {
        colsum[j] += __shfl_xor(colsum[j], 16);
        colsum[j] += __shfl_xor(colsum[j], 32);
    }
    if (quad == 0) {
#pragma unroll
        for (int j = 0; j < 4; j++)
            atomicAdd(&lsum[(size_t)n * L_ + ks * 64 + j * 16 + mr], colsum[j]);
    }
    __syncthreads();
    {
        int r = lane >> 1, c0 = (lane & 1) * 32;
        u16* dst = E + ((size_t)n * L_ + qs * 32 + r) * L_ + ks * 64 + c0;
#pragma unroll
        for (int c = 0; c < 32; c += 8)
            *(uint4*)(dst + c) = *(const uint4*)&Te[r][c0 + c];
    }
}

// ---------------------------------------------------------------
// K4: att[n,q,d] = sum_k E[q,k] * (vt[d,k]/lsum[k]).  1/lsum folded into
// the V-fragment load (same rounding as the old k3_vscale).  1-wave
// blocks, tile 64 q x 32 d, K=512.  grid (128 n, 8 qt, 4 ds), 64 thr.
// ---------------------------------------------------------------
__global__ __launch_bounds__(64) void k4_av(
    const u16* __restrict__ E, const u16* __restrict__ vtb,
    const float* __restrict__ lsum, u16* __restrict__ att) {
    const int n  = blockIdx.x;
    const int qt = blockIdx.y;
    const int ds = blockIdx.z;
    const int lane = threadIdx.x;
    const int mr = lane & 15, quad = lane >> 4;

    __shared__ float linvS[512];
    __shared__ __align__(16) u16 Ta[64][40];
    {
        const float* lp = lsum + (size_t)n * L_ + lane * 8;
        float4 a = *(const float4*)lp;
        float4 b = *(const float4*)(lp + 4);
        linvS[lane * 8 + 0] = 1.f / a.x; linvS[lane * 8 + 1] = 1.f / a.y;
        linvS[lane * 8 + 2] = 1.f / a.z; linvS[lane * 8 + 3] = 1.f / a.w;
        linvS[lane * 8 + 4] = 1.f / b.x; linvS[lane * 8 + 5] = 1.f / b.y;
        linvS[lane * 8 + 6] = 1.f / b.z; linvS[lane * 8 + 7] = 1.f / b.w;
    }
    __syncthreads();

    const u16* Eb = E + ((size_t)n * L_ + qt * 64) * L_;
    const u16* vb = vtb + ((size_t)n * D_ + ds * 32) * L_;

    f32x4 acc[4][2];
#pragma unroll
    for (int i = 0; i < 4; i++)
#pragma unroll
        for (int j = 0; j < 2; j++) acc[i][j] = (f32x4){0.f, 0.f, 0.f, 0.f};

    for (int k0 = 0; k0 < L_; k0 += 32) {
        s16x8 av[4], bv[2];
#pragma unroll
        for (int i = 0; i < 4; i++)
            av[i] = *(const s16x8*)(Eb + (size_t)(i * 16 + mr) * L_ + k0 + quad * 8);
        float lv[8];
        *(float4*)&lv[0] = *(const float4*)&linvS[k0 + quad * 8];
        *(float4*)&lv[4] = *(const float4*)&linvS[k0 + quad * 8 + 4];
#pragma unroll
        for (int j = 0; j < 2; j++) {
            s16x8 raw = *(const s16x8*)(vb + (size_t)(j * 16 + mr) * L_ + k0 + quad * 8);
            union { u16 u[8]; s16x8 v; } t;
#pragma unroll
            for (int s = 0; s < 8; s++)
                t.u[s] = f2bf(bf2f((u16)raw[s]) * lv[s]);
            bv[j] = t.v;
        }
#pragma unroll
        for (int i = 0; i < 4; i++)
#pragma unroll
            for (int j = 0; j < 2; j++)
                acc[i][j] = __builtin_amdgcn_mfma_f32_16x16x32_bf16(av[i], bv[j], acc[i][j], 0, 0, 0);
    }

#pragma unroll
    for (int i = 0; i < 4; i++)
#pragma unroll
        for (int j = 0; j < 2; j++) {
            int col = j * 16 + mr;
#pragma unroll
            for (int r = 0; r < 4; r++)
                Ta[i * 16 + quad * 4 + r][col] = f2bf(acc[i][j][r]);
        }
    __syncthreads();
    u16* dst = att + ((size_t)n * L_ + qt * 64 + lane) * D_ + ds * 32;
#pragma unroll
    for (int c = 0; c < 32; c += 8)
        *(uint4*)(dst + c) = *(const uint4*)&Ta[lane][c];
}

// ---------------------------------------------------------------
// K5: out = att_flat[8192][1024] @ Wo[128][1024]^T + bo (raw Wo/bo).
// grid (2 n-halves, 256 m-tiles of 32), 256 thr: 4 waves split K=1024,
// LDS fp32 reduction.  dt-switched output.
// ---------------------------------------------------------------
__global__ __launch_bounds__(256) void k5_out(
    const u16* __restrict__ att, const void* __restrict__ Wo,
    const void* __restrict__ bo, const int* __restrict__ flags,
    void* __restrict__ out) {
    const int dt = flags[0];
    const int n0 = blockIdx.x * 64;
    const int m0 = blockIdx.y * 32;
    const int tid = threadIdx.x;
    const int lane = tid & 63, wk = tid >> 6;
    const int mr = lane & 15, quad = lane >> 4;

    f32x4 acc[2][4];
#pragma unroll
    for (int i = 0; i < 2; i++)
#pragma unroll
        for (int j = 0; j < 4; j++) acc[i][j] = (f32x4){0.f, 0.f, 0.f, 0.f};

    mfma_core<2,4>(att, (size_t)m0 * HD_ + wk * 256, HD_, 1,
                   Wo, (size_t)n0 * HD_ + wk * 256, HD_, dt, 256, lane, acc);

    __shared__ __align__(16) float Tf[2][32][68];
    if (wk < 2) {
#pragma unroll
        for (int i = 0; i < 2; i++)
#pragma unroll
            for (int j = 0; j < 4; j++)
#pragma unroll
                for (int r = 0; r < 4; r++)
                    Tf[wk][i * 16 + quad * 4 + r][j * 16 + mr] = acc[i][j][r];
    }
    __syncthreads();
    if (wk >= 2) {
#pragma unroll
        for (int i = 0; i < 2; i++)
#pragma unroll
            for (int j = 0; j < 4; j++)
#pragma unroll
                for (int r = 0; r < 4; r++)
                    Tf[wk - 2][i * 16 + quad * 4 + r][j * 16 + mr] += acc[i][j][r];
    }
    __syncthreads();

    int row = tid >> 3, c0 = (tid & 7) * 8;
    size_t base = (size_t)(m0 + row) * D_ + n0 + c0;
    float v[8];
#pragma unroll
    for (int s = 0; s < 8; s++)
        v[s] = Tf[0][row][c0 + s] + Tf[1][row][c0 + s] + ld1(bo, n0 + c0 + s, dt);
    if (dt) {
        u16 tmp[8];
#pragma unroll
        for (int s = 0; s < 8; s++) tmp[s] = f2bf(v[s]);
        *(uint4*)((u16*)out + base) = *(const uint4*)tmp;
    } else {
        float* o = (float*)out;
        *(float4*)(o + base)     = *(const float4*)&v[0];
        *(float4*)(o + base + 4) = *(const float4*)&v[4];
    }
}

// ---------------------------------------------------------------
extern "C" void kernel_launch(void* const* d_in, const int* in_sizes, int n_in,
                              void* d_out, int out_size, void* d_ws, size_t ws_size,
                              hipStream_t stream) {
    (void)in_sizes; (void)n_in; (void)out_size; (void)ws_size;
    const void* x  = d_in[0];
    const void* Wq = d_in[1]; const void* bq = d_in[2];
    const void* Wk = d_in[3]; const void* bk = d_in[4];
    const void* Wv = d_in[5]; const void* bv = d_in[6];
    const void* Wo = d_in[7]; const void* bo = d_in[8];
    const void* pad = d_in[9];

    char* p = (char*)d_ws;
    auto alloc = [&](size_t bytes) { char* r = p; p += (bytes + 255) & ~(size_t)255; return r; };
    int*  flags = (int*)alloc(256);
    unsigned* mbits = (unsigned*)alloc(524288);
    float* lsum = (float*)alloc(262144);
    u16*  qb   = (u16*)alloc(16777216);
    u16*  kb   = (u16*)alloc(16777216);
    u16*  vtb  = (u16*)alloc(16777216);
    u16*  E    = (u16*)alloc(67108864);
    u16*  att  = qb;   // alias: qb's last read is k2; k4 writes att after

    k0_detect<<<1, 256, 0, stream>>>((const unsigned*)pad, (const unsigned*)x, flags);
    kprep_mask<<<512, 256, 0, stream>>>(pad, flags, mbits, lsum);
    k1_proj<<<dim3(128, 16, 3), 64, 0, stream>>>(
        x, Wq, Wk, Wv, bq, bk, bv, flags, qb, kb, vtb);
    k2_escore<<<dim3(128, 8, 16), 64, 0, stream>>>(qb, kb, mbits, E, lsum);
    k4_av<<<dim3(128, 8, 4), 64, 0, stream>>>(E, vtb, lsum, att);
    k5_out<<<dim3(2, 256), 256, 0, stream>>>(att, Wo, bo, flags, d_out);
}

// Round 8
// 262.551 us; speedup vs baseline: 1.1198x; 1.1198x over previous
//
#include <hip/hip_runtime.h>

// Problem constants (B, L, D, H) = (16, 512, 128, 8)
#define B_  16
#define L_  512
#define D_  128
#define H_  8
#define HD_ 1024   // H*D
#define NH_ 128    // H*B
#define M_  8192   // B*L

typedef unsigned short u16;
typedef __attribute__((ext_vector_type(8))) short s16x8;   // 8 bf16 = 4 VGPRs
typedef __attribute__((ext_vector_type(4))) float f32x4;   // MFMA accumulator

// ---------- bf16 helpers ----------
__device__ __forceinline__ float bf2f(u16 u) {
    union { unsigned u; float f; } x; x.u = ((unsigned)u) << 16; return x.f;
}
__device__ __forceinline__ u16 f2bf(float f) {
    unsigned u = __float_as_uint(f);
    return (u16)((u + 0x7FFFu + ((u >> 16) & 1u)) >> 16);   // RNE
}

// ---------------------------------------------------------------
// MFMA bt-core, COMPILE-TIME K (full unroll -> deep load pipelining).
// C(MI*16 x MJ*16) = A @ B^T for one wave.
// A/B operand: row = lane&15, k = (lane>>4)*8 + j  (16B contiguous)
// C/D: col = lane&15, row = (lane>>4)*4 + reg   (m89/m91-verified)
// ---------------------------------------------------------------
template<int MI, int MJ, int K>
__device__ __forceinline__ void mfma_bt(const u16* __restrict__ A, int lda,
                                        const u16* __restrict__ B, int ldb,
                                        int lane, f32x4 acc[MI][MJ]) {
    const int mr = lane & 15, quad = lane >> 4;
#pragma unroll
    for (int k0 = 0; k0 < K; k0 += 32) {
        s16x8 av[MI], bv[MJ];
#pragma unroll
        for (int i = 0; i < MI; i++)
            av[i] = *(const s16x8*)(A + (size_t)(i * 16 + mr) * lda + k0 + quad * 8);
#pragma unroll
        for (int j = 0; j < MJ; j++)
            bv[j] = *(const s16x8*)(B + (size_t)(j * 16 + mr) * ldb + k0 + quad * 8);
#pragma unroll
        for (int i = 0; i < MI; i++)
#pragma unroll
            for (int j = 0; j < MJ; j++)
                acc[i][j] = __builtin_amdgcn_mfma_f32_16x16x32_bf16(av[i], bv[j], acc[i][j], 0, 0, 0);
    }
}

// ---------------------------------------------------------------
// K0: detect float dtype (fp32 vs packed bf16) + mask dtype (i32 vs u8).
// ---------------------------------------------------------------
__global__ void k0_detect(const unsigned int* __restrict__ pad,
                          const unsigned int* __restrict__ xw,
                          int* __restrict__ flags) {
    __shared__ int sMask, sCnt;
    if (threadIdx.x == 0) { sMask = 0; sCnt = 0; }
    __syncthreads();
    int bad = 0;
#pragma unroll
    for (int i = 0; i < 4; i++) {
        unsigned u = pad[threadIdx.x * 4 + i];
        bad |= (u > 1u) ? 1 : 0;
    }
    int cnt = 0;
#pragma unroll
    for (int i = 0; i < 16; i++) {
        unsigned w = xw[threadIdx.x * 16 + i];
        unsigned e = (w >> 7) & 0xFFu;
        cnt += (e >= 100u && e <= 131u) ? 1 : 0;
    }
    if (bad) atomicOr(&sMask, 1);
    atomicAdd(&sCnt, cnt);
    __syncthreads();
    if (threadIdx.x == 0) {
        flags[0] = (sCnt > 2048) ? 1 : 0;   // 1 => floats are bf16
        flags[1] = sMask;                   // 1 => mask is uint8
    }
}

// ---------------------------------------------------------------
// Kprep: merged conv (blocks 0..769) + mask pack / lsum zero (770..1281).
// ---------------------------------------------------------------
#define PREP_G8 197008   // 1576064 / 8
__global__ __launch_bounds__(256) void kprep(
    const void* x, const void* Wq, const void* bq, const void* Wk, const void* bk,
    const void* Wv, const void* bv, const void* Wo, const void* bo,
    const void* __restrict__ pad, const int* __restrict__ flags,
    u16* xb, u16* Wqb, u16* Wkb, u16* Wvb, u16* Wob,
    u16* bqb, u16* bkb, u16* bvb, u16* bob,
    unsigned* __restrict__ mb, float* __restrict__ lsum) {
    if (blockIdx.x < 770) {
        int g = blockIdx.x * 256 + threadIdx.x;
        if (g >= PREP_G8) return;
        int e0 = g * 8;
        const int dt = flags[0];
        const void* src; u16* dst; int off;
        if      (e0 < 1048576) { src = x;  dst = xb;  off = e0; }
        else if (e0 < 1179648) { src = Wq; dst = Wqb; off = e0 - 1048576; }
        else if (e0 < 1310720) { src = Wk; dst = Wkb; off = e0 - 1179648; }
        else if (e0 < 1441792) { src = Wv; dst = Wvb; off = e0 - 1310720; }
        else if (e0 < 1572864) { src = Wo; dst = Wob; off = e0 - 1441792; }
        else if (e0 < 1573888) { src = bq; dst = bqb; off = e0 - 1572864; }
        else if (e0 < 1574912) { src = bk; dst = bkb; off = e0 - 1573888; }
        else if (e0 < 1575936) { src = bv; dst = bvb; off = e0 - 1574912; }
        else                   { src = bo; dst = bob; off = e0 - 1575936; }
        if (dt) {
            *(uint4*)(dst + off) = *(const uint4*)((const u16*)src + off);
        } else {
            float4 a = *(const float4*)((const float*)src + off);
            float4 b = *(const float4*)((const float*)src + off + 4);
            u16 t[8] = {f2bf(a.x), f2bf(a.y), f2bf(a.z), f2bf(a.w),
                        f2bf(b.x), f2bf(b.y), f2bf(b.z), f2bf(b.w)};
            *(uint4*)(dst + off) = *(const uint4*)t;
        }
    } else {
        int w = (blockIdx.x - 770) * 256 + threadIdx.x;  // < 131072
        if (w < 65536) lsum[w] = 0.f;
        unsigned m = 0;
        if (flags[1]) {
            union { uint4 v[2]; unsigned a[8]; } u;
            u.v[0] = ((const uint4*)pad)[w * 2];
            u.v[1] = ((const uint4*)pad)[w * 2 + 1];
#pragma unroll
            for (int b = 0; b < 32; b++)
                m |= (((u.a[b >> 2] >> ((b & 3) * 8)) & 0xFFu) ? 1u : 0u) << b;
        } else {
            union { uint4 v[8]; unsigned a[32]; } u;
#pragma unroll
            for (int i = 0; i < 8; i++) u.v[i] = ((const uint4*)pad)[w * 8 + i];
#pragma unroll
            for (int b = 0; b < 32; b++) m |= (u.a[b] ? 1u : 0u) << b;
        }
        mb[w] = m;
    }
}

// ---------------------------------------------------------------
// K1: QKV projection via MFMA (prep'd bf16 inputs).  y = x @ W^T + b.
// q,k head-major [n][l][d]; v TRANSPOSED [n][d][l] (unscaled).
// grid (8 heads, 64 m-tiles, 3), 256 threads.
// ---------------------------------------------------------------
__global__ __launch_bounds__(256) void k1_proj(
    const u16* __restrict__ xb,
    const u16* __restrict__ Wqb, const u16* __restrict__ Wkb, const u16* __restrict__ Wvb,
    const u16* __restrict__ bqb, const u16* __restrict__ bkb, const u16* __restrict__ bvb,
    u16* __restrict__ qb, u16* __restrict__ kb, u16* __restrict__ vtb) {
    const int h  = blockIdx.x;
    const int m0 = blockIdx.y * 128;
    const int z  = blockIdx.z;
    const u16* W    = (z == 0) ? Wqb : (z == 1) ? Wkb : Wvb;
    const u16* bias = (z == 0) ? bqb : (z == 1) ? bkb : bvb;

    const int lane = threadIdx.x & 63, wave = threadIdx.x >> 6;
    const int wr = wave >> 1, wc = wave & 1;
    const int mr = lane & 15, quad = lane >> 4;

    f32x4 acc[4][4];
#pragma unroll
    for (int i = 0; i < 4; i++)
#pragma unroll
        for (int j = 0; j < 4; j++) acc[i][j] = (f32x4){0.f, 0.f, 0.f, 0.f};

    mfma_bt<4,4,128>(xb + (size_t)(m0 + wr * 64) * D_, D_,
                     W + (size_t)(h * 128 + wc * 64) * D_, D_, lane, acc);

    __shared__ __align__(16) u16 T[128][136];
#pragma unroll
    for (int i = 0; i < 4; i++)
#pragma unroll
        for (int j = 0; j < 4; j++) {
            int col = wc * 64 + j * 16 + mr;
            float bv_ = bf2f(bias[h * 128 + col]);
#pragma unroll
            for (int r = 0; r < 4; r++)
                T[wr * 64 + i * 16 + quad * 4 + r][col] = f2bf(acc[i][j][r] + bv_);
        }
    __syncthreads();

    const int bb = m0 >> 9, l0 = m0 & 511;
    const int t = threadIdx.x;
    if (z < 2) {
        u16* out = z ? kb : qb;
        int row = t >> 1, c0 = (t & 1) * 64;
        u16* dst = out + ((size_t)(h * B_ + bb) * L_ + l0 + row) * D_ + c0;
#pragma unroll
        for (int c = 0; c < 64; c += 8)
            *(uint4*)(dst + c) = *(const uint4*)&T[row][c0 + c];
    } else {
        int d = t >> 1, lc0 = (t & 1) * 64;
        u16* dst = vtb + ((size_t)(h * B_ + bb) * D_ + d) * L_ + l0 + lc0;
#pragma unroll
        for (int c = 0; c < 64; c += 8) {
            u16 tmp[8];
#pragma unroll
            for (int s = 0; s < 8; s++) tmp[s] = T[lc0 + c + s][d];
            *(uint4*)(dst + c) = *(const uint4*)tmp;
        }
    }
}

// ---------------------------------------------------------------
// K2: E[n,q,k] = exp((mask? -1e9 : q.k) * rs), bf16, plus column-sum
// partials atomically added to lsum[n,k].  Tile 64q x 128k, 4 waves
// with DISJOINT 32-k slices (no cross-wave reduce).  LDS 18.5 KB ->
// 8 blocks/CU.  grid (128 n, 4 ks, 8 qs), 256 threads, 2 barriers.
// ---------------------------------------------------------------
__global__ __launch_bounds__(256) void k2_escore(
    const u16* __restrict__ qb, const u16* __restrict__ kb,
    const unsigned* __restrict__ mbits,
    u16* __restrict__ E, float* __restrict__ lsum) {
    const int n  = blockIdx.x;
    const int ks = blockIdx.y;       // k-strip of 128
    const int qs = blockIdx.z;       // q-strip of 64
    const int bb = n & (B_ - 1);
    const int tid = threadIdx.x;
    const int lane = tid & 63, w = tid >> 6;
    const int mr = lane & 15, quad = lane >> 4;
    const float rs = 0.08838834764831845f;   // 1/sqrt(128)

    __shared__ __align__(16) u16 Te[64][136];
    __shared__ unsigned mw[256];             // [64 q][4 words of strip]
    mw[tid] = mbits[((size_t)(bb << 9) + qs * 64 + (tid >> 2)) * 16 + ks * 4 + (tid & 3)];
    __syncthreads();

    f32x4 acc[4][2];
#pragma unroll
    for (int i = 0; i < 4; i++)
#pragma unroll
        for (int j = 0; j < 2; j++) acc[i][j] = (f32x4){0.f, 0.f, 0.f, 0.f};

    mfma_bt<4,2,128>(qb + ((size_t)n * L_ + qs * 64) * D_, D_,
                     kb + ((size_t)n * L_ + ks * 128 + w * 32) * D_, D_, lane, acc);

    float colsum[2] = {0.f, 0.f};
#pragma unroll
    for (int j = 0; j < 2; j++) {
        const int kcL = w * 32 + j * 16 + mr;    // 0..127 within strip
        const int word = kcL >> 5, bit = kcL & 31;
#pragma unroll
        for (int i = 0; i < 4; i++)
#pragma unroll
            for (int r = 0; r < 4; r++) {
                int ql = i * 16 + quad * 4 + r;
                float e = ((mw[ql * 4 + word] >> bit) & 1u)
                          ? 0.f : __expf(acc[i][j][r] * rs);
                colsum[j] += e;
                Te[ql][kcL] = f2bf(e);
            }
    }
#pragma unroll
    for (int j = 0; j < 2; j++) {
        colsum[j] += __shfl_xor(colsum[j], 16);
        colsum[j] += __shfl_xor(colsum[j], 32);
    }
    if (quad == 0) {
#pragma unroll
        for (int j = 0; j < 2; j++)
            atomicAdd(&lsum[(size_t)n * L_ + ks * 128 + w * 32 + j * 16 + mr], colsum[j]);
    }
    __syncthreads();
    {
        int row = tid >> 2, c0 = (tid & 3) * 32;
        u16* dst = E + ((size_t)n * L_ + qs * 64 + row) * L_ + ks * 128 + c0;
#pragma unroll
        for (int c = 0; c < 32; c += 8)
            *(uint4*)(dst + c) = *(const uint4*)&Te[row][c0 + c];
    }
}

// ---------------------------------------------------------------
// K4: att[n,q,d] = sum_k E[q,k] * (vt[d,k]/lsum[k]); 1/lsum folded into
// the V-fragment load (same rounding as a separate vscale pass).
// grid (128 n, 8 qt), 256 thr; wave w -> 64q x 32d slice, K=512
// unrolled x4.
// ---------------------------------------------------------------
__global__ __launch_bounds__(256) void k4_av(
    const u16* __restrict__ E, const u16* __restrict__ vtb,
    const float* __restrict__ lsum, u16* __restrict__ att) {
    const int n  = blockIdx.x;
    const int qt = blockIdx.y;
    const int tid = threadIdx.x;
    const int lane = tid & 63, w = tid >> 6;
    const int mr = lane & 15, quad = lane >> 4;

    __shared__ float linvS[512];
    __shared__ __align__(16) u16 Ta[64][136];
    if (tid < 128) {
        const float* lp = lsum + (size_t)n * L_ + tid * 4;
        float4 a = *(const float4*)lp;
        linvS[tid * 4 + 0] = 1.f / a.x; linvS[tid * 4 + 1] = 1.f / a.y;
        linvS[tid * 4 + 2] = 1.f / a.z; linvS[tid * 4 + 3] = 1.f / a.w;
    }
    __syncthreads();

    const u16* Eb = E + ((size_t)n * L_ + qt * 64) * L_;
    const u16* vb = vtb + ((size_t)n * D_ + w * 32) * L_;

    f32x4 acc[4][2];
#pragma unroll
    for (int i = 0; i < 4; i++)
#pragma unroll
        for (int j = 0; j < 2; j++) acc[i][j] = (f32x4){0.f, 0.f, 0.f, 0.f};

#pragma unroll 4
    for (int k0 = 0; k0 < L_; k0 += 32) {
        s16x8 av[4], bv[2];
#pragma unroll
        for (int i = 0; i < 4; i++)
            av[i] = *(const s16x8*)(Eb + (size_t)(i * 16 + mr) * L_ + k0 + quad * 8);
        float lv[8];
        *(float4*)&lv[0] = *(const float4*)&linvS[k0 + quad * 8];
        *(float4*)&lv[4] = *(const float4*)&linvS[k0 + quad * 8 + 4];
#pragma unroll
        for (int j = 0; j < 2; j++) {
            s16x8 raw = *(const s16x8*)(vb + (size_t)(j * 16 + mr) * L_ + k0 + quad * 8);
            union { u16 u[8]; s16x8 v; } t;
#pragma unroll
            for (int s = 0; s < 8; s++)
                t.u[s] = f2bf(bf2f((u16)raw[s]) * lv[s]);
            bv[j] = t.v;
        }
#pragma unroll
        for (int i = 0; i < 4; i++)
#pragma unroll
            for (int j = 0; j < 2; j++)
                acc[i][j] = __builtin_amdgcn_mfma_f32_16x16x32_bf16(av[i], bv[j], acc[i][j], 0, 0, 0);
    }

#pragma unroll
    for (int i = 0; i < 4; i++)
#pragma unroll
        for (int j = 0; j < 2; j++) {
            int col = w * 32 + j * 16 + mr;
#pragma unroll
            for (int r = 0; r < 4; r++)
                Ta[i * 16 + quad * 4 + r][col] = f2bf(acc[i][j][r]);
        }
    __syncthreads();
    {
        int row = tid >> 2, c0 = (tid & 3) * 32;
        u16* dst = att + ((size_t)n * L_ + qt * 64 + row) * D_ + c0;
#pragma unroll
        for (int c = 0; c < 32; c += 8)
            *(uint4*)(dst + c) = *(const uint4*)&Ta[row][c0 + c];
    }
}

// ---------------------------------------------------------------
// K5: out = att_flat[8192][1024] @ Wo[128][1024]^T + bo.
// grid (2 n-halves, 256 m-tiles of 32), 256 thr: 4 waves split K=1024
// into 256 each (compile-time), LDS fp32 reduction.  dt-switched output.
// ---------------------------------------------------------------
__global__ __launch_bounds__(256) void k5_out(
    const u16* __restrict__ att, const u16* __restrict__ Wob,
    const u16* __restrict__ bob, const int* __restrict__ flags,
    void* __restrict__ out) {
    const int dt = flags[0];
    const int n0 = blockIdx.x * 64;
    const int m0 = blockIdx.y * 32;
    const int tid = threadIdx.x;
    const int lane = tid & 63, wk = tid >> 6;
    const int mr = lane & 15, quad = lane >> 4;

    f32x4 acc[2][4];
#pragma unroll
    for (int i = 0; i < 2; i++)
#pragma unroll
        for (int j = 0; j < 4; j++) acc[i][j] = (f32x4){0.f, 0.f, 0.f, 0.f};

    mfma_bt<2,4,256>(att + (size_t)m0 * HD_ + wk * 256, HD_,
                     Wob + (size_t)n0 * HD_ + wk * 256, HD_, lane, acc);

    __shared__ __align__(16) float Tf[2][32][68];
    if (wk < 2) {
#pragma unroll
        for (int i = 0; i < 2; i++)
#pragma unroll
            for (int j = 0; j < 4; j++)
#pragma unroll
                for (int r = 0; r < 4; r++)
                    Tf[wk][i * 16 + quad * 4 + r][j * 16 + mr] = acc[i][j][r];
    }
    __syncthreads();
    if (wk >= 2) {
#pragma unroll
        for (int i = 0; i < 2; i++)
#pragma unroll
            for (int j = 0; j < 4; j++)
#pragma unroll
                for (int r = 0; r < 4; r++)
                    Tf[wk - 2][i * 16 + quad * 4 + r][j * 16 + mr] += acc[i][j][r];
    }
    __syncthreads();

    int row = tid >> 3, c0 = (tid & 7) * 8;
    size_t base = (size_t)(m0 + row) * D_ + n0 + c0;
    float v[8];
#pragma unroll
    for (int s = 0; s < 8; s++)
        v[s] = Tf[0][row][c0 + s] + Tf[1][row][c0 + s] + bf2f(bob[n0 + c0 + s]);
    if (dt) {
        u16 tmp[8];
#pragma unroll
        for (int s = 0; s < 8; s++) tmp[s] = f2bf(v[s]);
        *(uint4*)((u16*)out + base) = *(const uint4*)tmp;
    } else {
        float* o = (float*)out;
        *(float4*)(o + base)     = *(const float4*)&v[0];
        *(float4*)(o + base + 4) = *(const float4*)&v[4];
    }
}

// ---------------------------------------------------------------
extern "C" void kernel_launch(void* const* d_in, const int* in_sizes, int n_in,
                              void* d_out, int out_size, void* d_ws, size_t ws_size,
                              hipStream_t stream) {
    (void)in_sizes; (void)n_in; (void)out_size; (void)ws_size;
    const void* x  = d_in[0];
    const void* Wq = d_in[1]; const void* bq = d_in[2];
    const void* Wk = d_in[3]; const void* bk = d_in[4];
    const void* Wv = d_in[5]; const void* bv = d_in[6];
    const void* Wo = d_in[7]; const void* bo = d_in[8];
    const void* pad = d_in[9];

    char* p = (char*)d_ws;
    auto alloc = [&](size_t bytes) { char* r = p; p += (bytes + 255) & ~(size_t)255; return r; };
    int*  flags = (int*)alloc(256);
    u16*  xb   = (u16*)alloc(2097152);
    u16*  Wqb  = (u16*)alloc(262144);
    u16*  Wkb  = (u16*)alloc(262144);
    u16*  Wvb  = (u16*)alloc(262144);
    u16*  Wob  = (u16*)alloc(262144);
    u16*  bqb  = (u16*)alloc(2048);
    u16*  bkb  = (u16*)alloc(2048);
    u16*  bvb  = (u16*)alloc(2048);
    u16*  bob  = (u16*)alloc(256);
    unsigned* mbits = (unsigned*)alloc(524288);
    float* lsum = (float*)alloc(262144);
    u16*  qb   = (u16*)alloc(16777216);
    u16*  kb   = (u16*)alloc(16777216);
    u16*  vtb  = (u16*)alloc(16777216);
    u16*  E    = (u16*)alloc(67108864);
    u16*  att  = qb;   // alias: qb's last read is k2; k4 writes att after

    k0_detect<<<1, 256, 0, stream>>>((const unsigned*)pad, (const unsigned*)x, flags);
    kprep<<<1282, 256, 0, stream>>>(
        x, Wq, bq, Wk, bk, Wv, bv, Wo, bo, pad, flags,
        xb, Wqb, Wkb, Wvb, Wob, bqb, bkb, bvb, bob, mbits, lsum);
    k1_proj<<<dim3(8, 64, 3), 256, 0, stream>>>(
        xb, Wqb, Wkb, Wvb, bqb, bkb, bvb, qb, kb, vtb);
    k2_escore<<<dim3(128, 4, 8), 256, 0, stream>>>(qb, kb, mbits, E, lsum);
    k4_av<<<dim3(128, 8), 256, 0, stream>>>(E, vtb, lsum, att);
    k5_out<<<dim3(2, 256), 256, 0, stream>>>(att, Wob, bob, flags, d_out);
}